// Round 1
// baseline (159.671 us; speedup 1.0000x reference)
//
#include <hip/hip_runtime.h>

#define NPG 28      // nodes per graph
#define EPG 56      // edges per graph
#define ROWS 56     // rows per pair (2 graphs)
#define EDG 112     // edges per pair
#define CH 128
#define LDW 136     // LDS leading dim (bf16 elems), +8 pad -> 272B row stride

typedef float f32x4 __attribute__((ext_vector_type(4)));
typedef __bf16 bf16x8 __attribute__((ext_vector_type(8)));
typedef unsigned short u16;
typedef u16 u16x8 __attribute__((ext_vector_type(8)));
typedef u16 u16x4 __attribute__((ext_vector_type(4)));

__device__ __forceinline__ u16 f2bf(float f){
  union { float f; unsigned u; } v; v.f = f;
  unsigned r = (v.u + 0x7fffu + ((v.u >> 16) & 1u)) >> 16;  // RNE
  return (u16)r;
}
__device__ __forceinline__ float bf2f(u16 h){
  union { unsigned u; float f; } v; v.u = ((unsigned)h) << 16;
  return v.f;
}

__global__ __launch_bounds__(256, 2)
void gcn_fused(const float* __restrict__ x, const int* __restrict__ ei,
               const float* __restrict__ W, const float* __restrict__ bias,
               const float* __restrict__ ew, const float* __restrict__ gamma,
               const float* __restrict__ beta, float* __restrict__ out,
               int npairs)
{
  __shared__ alignas(16) u16 Wt[CH][LDW];     // Wt[c][k] = W[k][c], bf16
  __shared__ alignas(16) u16 Hs[ROWS][LDW];   // h = xW, bf16
  __shared__ alignas(16) float gam[CH], bet[CH], bia[CH];
  __shared__ float evw[EPG];
  __shared__ float deg[ROWS];                 // deg, then dinv
  __shared__ int   cnt[ROWS];
  __shared__ int   rs[ROWS + 1];              // CSR row starts
  __shared__ int   c_src[EDG];
  __shared__ float c_nrm[EDG];

  const int tid  = threadIdx.x;
  const int lane = tid & 63;
  const int wv   = tid >> 6;
  const int Etot = npairs * EDG;

  // one-time per-block staging
  for (int i = tid; i < CH * CH; i += 256){
    Wt[i & (CH - 1)][i >> 7] = f2bf(W[i]);    // transpose: coalesced global read
  }
  if (tid < EPG) evw[tid] = ew[tid];
  if (tid < CH){ gam[tid] = gamma[tid]; bet[tid] = beta[tid]; bia[tid] = bias[tid]; }

  for (int p = blockIdx.x; p < npairs; p += gridDim.x){
    __syncthreads();   // protects Wt first use + Hs/CSR reuse across iterations

    // ---- phase A: edge meta into regs, deg init, GEMM ----
    int es = 0, ed = 0; float eww = 0.f;
    if (tid < ROWS) deg[tid] = 1.0f;          // self-loop weight
    if (tid < EDG){
      es  = ei[p * EDG + tid]        - p * ROWS;   // local row in [0,56)
      ed  = ei[Etot + p * EDG + tid] - p * ROWS;
      eww = evw[(tid >= EPG) ? (tid - EPG) : tid];
    }

    // GEMM: wave wv owns rows [16wv, 16wv+16); A-frags straight from global
    int arow = 16 * wv + (lane & 15);
    int grow = p * ROWS + (arow < ROWS ? arow : ROWS - 1);   // clamp pad rows
    const float* xp = x + (size_t)grow * CH + ((lane >> 4) * 8);
    bf16x8 afr[4];
#pragma unroll
    for (int ks = 0; ks < 4; ks++){
      f32x4 lo = *(const f32x4*)(xp + ks * 32);
      f32x4 hi = *(const f32x4*)(xp + ks * 32 + 4);
      u16x8 t;
      t[0] = f2bf(lo[0]); t[1] = f2bf(lo[1]); t[2] = f2bf(lo[2]); t[3] = f2bf(lo[3]);
      t[4] = f2bf(hi[0]); t[5] = f2bf(hi[1]); t[6] = f2bf(hi[2]); t[7] = f2bf(hi[3]);
      afr[ks] = __builtin_bit_cast(bf16x8, t);
    }
    f32x4 acc[8];
#pragma unroll
    for (int ct = 0; ct < 8; ct++){
      acc[ct] = (f32x4){0.f, 0.f, 0.f, 0.f};
      const u16* wp = &Wt[16 * ct + (lane & 15)][(lane >> 4) * 8];
#pragma unroll
      for (int ks = 0; ks < 4; ks++){
        u16x8 b = *(const u16x8*)(wp + ks * 32);
        acc[ct] = __builtin_amdgcn_mfma_f32_16x16x32_bf16(
                    afr[ks], __builtin_bit_cast(bf16x8, b), acc[ct], 0, 0, 0);
      }
    }
    {
      int r0 = 16 * wv + ((lane >> 4) << 2);
      int cc = lane & 15;
#pragma unroll
      for (int ct = 0; ct < 8; ct++){
#pragma unroll
        for (int r = 0; r < 4; r++){
          int rr = r0 + r;
          if (rr < ROWS) Hs[rr][16 * ct + cc] = f2bf(acc[ct][r]);
        }
      }
    }
    __syncthreads();

    // ---- phase B: degree accumulate ----
    if (tid < EDG) atomicAdd(&deg[ed], eww);
    __syncthreads();
    // ---- phase C: dinv, reset counters ----
    if (tid < ROWS){ deg[tid] = rsqrtf(deg[tid]); cnt[tid] = 0; }
    __syncthreads();
    // ---- phase D: edge norm + indegree count ----
    float nrm = 0.f;
    if (tid < EDG){
      nrm = deg[es] * eww * deg[ed];
      atomicAdd(&cnt[ed], 1);
    }
    __syncthreads();
    // ---- phase E: CSR offsets via wave-0 inclusive scan ----
    if (wv == 0){
      int v = (lane < ROWS) ? cnt[lane] : 0;
#pragma unroll
      for (int off = 1; off < 64; off <<= 1){
        int n = __shfl_up(v, off, 64);
        if (lane >= off) v += n;
      }
      if (lane < ROWS){ rs[lane + 1] = v; cnt[lane] = 0; }
      if (lane == 0) rs[0] = 0;
    }
    __syncthreads();
    // ---- phase F: CSR fill ----
    if (tid < EDG){
      int slot = rs[ed] + atomicAdd(&cnt[ed], 1);
      c_src[slot] = es;
      c_nrm[slot] = nrm;
    }
    __syncthreads();

    // ---- phase G: gather + bias + residual + LN + ReLU + store ----
    // wave owns 2 rows per step: lanes 0-31 -> row 2rp, lanes 32-63 -> row 2rp+1
    int half = lane >> 5;
    int l32  = lane & 31;
    int c0   = l32 * 4;
    for (int rp = wv; rp < ROWS / 2; rp += 4){
      int row = 2 * rp + half;
      float dv = deg[row];
      float d2 = dv * dv;                         // self-loop norm
      size_t gbase = (size_t)(p * ROWS + row) * CH + c0;
      u16x4 hs = *(const u16x4*)&Hs[row][c0];
      f32x4 xr = *(const f32x4*)(x + gbase);      // residual (L2-hot)
      f32x4 bb = *(const f32x4*)&bia[c0];
      float y0 = bf2f(hs[0]) * d2 + bb[0] + xr[0];
      float y1 = bf2f(hs[1]) * d2 + bb[1] + xr[1];
      float y2 = bf2f(hs[2]) * d2 + bb[2] + xr[2];
      float y3 = bf2f(hs[3]) * d2 + bb[3] + xr[3];
      int s0 = rs[row], s1 = rs[row + 1];
      for (int i = s0; i < s1; i++){
        int sc = c_src[i]; float nm = c_nrm[i];
        u16x4 hv = *(const u16x4*)&Hs[sc][c0];
        y0 += nm * bf2f(hv[0]);
        y1 += nm * bf2f(hv[1]);
        y2 += nm * bf2f(hv[2]);
        y3 += nm * bf2f(hv[3]);
      }
      float sm = y0 + y1 + y2 + y3;
      float sq = y0*y0 + y1*y1 + y2*y2 + y3*y3;
#pragma unroll
      for (int m = 1; m < 32; m <<= 1){
        sm += __shfl_xor(sm, m, 32);
        sq += __shfl_xor(sq, m, 32);
      }
      float mu   = sm * (1.0f / 128.0f);
      float var  = sq * (1.0f / 128.0f) - mu * mu;
      float rstd = rsqrtf(var + 1e-5f);
      f32x4 g4 = *(const f32x4*)&gam[c0];
      f32x4 b4 = *(const f32x4*)&bet[c0];
      f32x4 o;
      o[0] = fmaxf(0.f, (y0 - mu) * rstd * g4[0] + b4[0]);
      o[1] = fmaxf(0.f, (y1 - mu) * rstd * g4[1] + b4[1]);
      o[2] = fmaxf(0.f, (y2 - mu) * rstd * g4[2] + b4[2]);
      o[3] = fmaxf(0.f, (y3 - mu) * rstd * g4[3] + b4[3]);
      *(f32x4*)(out + gbase) = o;
    }
  }
}

extern "C" void kernel_launch(void* const* d_in, const int* in_sizes, int n_in,
                              void* d_out, int out_size, void* d_ws, size_t ws_size,
                              hipStream_t stream)
{
  const float* x     = (const float*)d_in[0];
  const int*   ei    = (const int*)d_in[1];
  const float* W     = (const float*)d_in[2];
  const float* bias  = (const float*)d_in[3];
  const float* ew    = (const float*)d_in[4];
  const float* gamma = (const float*)d_in[5];
  const float* beta  = (const float*)d_in[6];
  float* out = (float*)d_out;

  int N = in_sizes[0] / CH;        // 458752
  int npairs = N / ROWS;           // 8192
  int grid = npairs < 2048 ? npairs : 2048;
  hipLaunchKernelGGL(gcn_fused, dim3(grid), dim3(256), 0, stream,
                     x, ei, W, bias, ew, gamma, beta, out, npairs);
}

// Round 2
// 138.038 us; speedup vs baseline: 1.1567x; 1.1567x over previous
//
#include <hip/hip_runtime.h>

#define NPG 28
#define EPG 56
#define ROWS 56      // rows per pair (2 graphs)
#define EDG 112      // edges per pair
#define CH 128
#define LDW 136      // Hs leading dim (bf16), +8 pad

typedef float f32x4 __attribute__((ext_vector_type(4)));
typedef __bf16 bf16x8 __attribute__((ext_vector_type(8)));
typedef unsigned short u16;
typedef u16 u16x8 __attribute__((ext_vector_type(8)));
typedef u16 u16x4 __attribute__((ext_vector_type(4)));

__device__ __forceinline__ u16 f2bf(float f){
  union { float f; unsigned u; } v; v.f = f;
  unsigned r = (v.u + 0x7fffu + ((v.u >> 16) & 1u)) >> 16;  // RNE
  return (u16)r;
}
__device__ __forceinline__ float bf2f(u16 h){
  union { unsigned u; float f; } v; v.u = ((unsigned)h) << 16;
  return v.f;
}

// Pre-kernel: pack W (f32 [128][128]) into MFMA B-fragment order, bf16.
// Bpack[((ct*4+ks)*64 + l)*8 + j] = bf16( W[(l>>4)*8 + ks*32 + j][ct*16 + (l&15)] )
__global__ void pack_w(const float* __restrict__ W, u16* __restrict__ wp){
  int d = blockIdx.x * 256 + threadIdx.x;           // 0..16383
  int j  = d & 7;
  int l  = (d >> 3) & 63;
  int ks = (d >> 9) & 3;
  int ct = d >> 11;
  int k = ((l >> 4) << 3) + (ks << 5) + j;
  int c = (ct << 4) + (l & 15);
  wp[d] = f2bf(W[k * CH + c]);
}

__global__ __launch_bounds__(512, 4)
void gcn_fused(const float* __restrict__ x, const int* __restrict__ ei,
               const float* __restrict__ W, const float* __restrict__ bias,
               const float* __restrict__ ew, const float* __restrict__ gamma,
               const float* __restrict__ beta, float* __restrict__ out,
               const u16* __restrict__ wpack, int npairs)
{
  __shared__ alignas(16) u16 Bp[16384];         // packed W frags (32 KB)
  __shared__ alignas(16) u16 Hs[2][ROWS][LDW];  // h bf16, per pair
  __shared__ float gam[CH], bet[CH], bia[CH], evw[EPG];
  __shared__ float deg[2][ROWS];                // deg -> dinv
  __shared__ int   cnt[2][ROWS], cnt2[2][ROWS], rs[2][ROWS + 1];
  __shared__ int   c_src[2][EDG];
  __shared__ float c_nrm[2][EDG];

  const int tid  = threadIdx.x;
  const int lane = tid & 63;
  const int s    = tid >> 8;          // which pair of the block (0/1)
  const int wv4  = (tid >> 6) & 3;    // wave within pair
  const int t256 = tid & 255;
  const int ngroups = npairs >> 1;
  const int Etot = npairs * EDG;

  // ---- one-time staging ----
  if (wpack){
    for (int it = 0; it < 4; ++it){
      int idx = it * 512 + tid;                 // 16B unit
      *(u16x8*)&Bp[idx * 8] = ((const u16x8*)wpack)[idx];
    }
  } else {
    for (int i = tid; i < CH * CH; i += 512){
      int j = i & 7, l = (i >> 3) & 63, ks = (i >> 9) & 3, ct = i >> 11;
      int k = ((l >> 4) << 3) + (ks << 5) + j;
      int c = (ct << 4) + (l & 15);
      Bp[i] = f2bf(W[k * CH + c]);
    }
  }
  if (tid < EPG) evw[tid] = ew[tid];
  if (tid < CH){ gam[tid] = gamma[tid]; bet[tid] = beta[tid]; bia[tid] = bias[tid]; }

  // A-frag addressing: row within pair
  const int arow = 16 * wv4 + (lane & 15);
  const int rowc = arow < ROWS ? arow : ROWS - 1;   // clamp pad rows
  const int xoff = (lane >> 4) * 8;

  // prologue: prefetch first group's A rows (f32)
  f32x4 pf[8];
  {
    int p0 = 2 * blockIdx.x + s;
    const float* xp = x + ((size_t)p0 * ROWS + rowc) * CH + xoff;
#pragma unroll
    for (int ks = 0; ks < 4; ks++){
      pf[2 * ks]     = *(const f32x4*)(xp + ks * 32);
      pf[2 * ks + 1] = *(const f32x4*)(xp + ks * 32 + 4);
    }
  }

  for (int q = blockIdx.x; q < ngroups; q += gridDim.x){
    const int p = 2 * q + s;
    __syncthreads();   // sync0: protects Bp first use + Hs/deg/CSR reuse

    // ---- phase A: edge meta, init, GEMM, Hs write, next-prefetch ----
    int es = 0, ed = 0; float eww = 0.f;
    if (t256 < EDG){
      es  = ei[p * EDG + t256]        - p * ROWS;
      ed  = ei[Etot + p * EDG + t256] - p * ROWS;
      eww = evw[(t256 >= EPG) ? (t256 - EPG) : t256];
    }
    if (t256 < ROWS){ deg[s][t256] = 1.0f; cnt[s][t256] = 0; cnt2[s][t256] = 0; }

    bf16x8 afr[4];
#pragma unroll
    for (int ks = 0; ks < 4; ks++){
      f32x4 lo = pf[2 * ks], hi = pf[2 * ks + 1];
      u16x8 t;
      t[0] = f2bf(lo[0]); t[1] = f2bf(lo[1]); t[2] = f2bf(lo[2]); t[3] = f2bf(lo[3]);
      t[4] = f2bf(hi[0]); t[5] = f2bf(hi[1]); t[6] = f2bf(hi[2]); t[7] = f2bf(hi[3]);
      afr[ks] = __builtin_bit_cast(bf16x8, t);
    }
    f32x4 acc[8];
#pragma unroll
    for (int ct = 0; ct < 8; ct++){
      acc[ct] = (f32x4){0.f, 0.f, 0.f, 0.f};
#pragma unroll
      for (int ks = 0; ks < 4; ks++){
        u16x8 b = *(const u16x8*)&Bp[(((ct << 2) + ks) * 64 + lane) * 8];
        acc[ct] = __builtin_amdgcn_mfma_f32_16x16x32_bf16(
                    afr[ks], __builtin_bit_cast(bf16x8, b), acc[ct], 0, 0, 0);
      }
    }
    {
      int r0 = 16 * wv4 + ((lane >> 4) << 2);
      int cc = lane & 15;
#pragma unroll
      for (int ct = 0; ct < 8; ct++){
#pragma unroll
        for (int r = 0; r < 4; r++){
          int rr = r0 + r;
          if (rr < ROWS) Hs[s][rr][16 * ct + cc] = f2bf(acc[ct][r]);
        }
      }
    }
    // prefetch next group's A rows (hidden under phases B..G)
    {
      int qn = q + (int)gridDim.x; if (qn >= ngroups) qn = q;
      int pn = 2 * qn + s;
      const float* xp = x + ((size_t)pn * ROWS + rowc) * CH + xoff;
#pragma unroll
      for (int ks = 0; ks < 4; ks++){
        pf[2 * ks]     = *(const f32x4*)(xp + ks * 32);
        pf[2 * ks + 1] = *(const f32x4*)(xp + ks * 32 + 4);
      }
    }
    __syncthreads();   // sync1: Hs + deg/cnt init visible

    // ---- phase B: degree + indegree count ----
    if (t256 < EDG){
      atomicAdd(&deg[s][ed], eww);
      atomicAdd(&cnt[s][ed], 1);
    }
    __syncthreads();   // sync2

    // ---- phase C: dinv + CSR offsets (scan by wave 0 of each pair) ----
    if (t256 < ROWS) deg[s][t256] = rsqrtf(deg[s][t256]);
    if (wv4 == 0){
      int v = (lane < ROWS) ? cnt[s][lane] : 0;
#pragma unroll
      for (int off = 1; off < 64; off <<= 1){
        int n = __shfl_up(v, off, 64);
        if (lane >= off) v += n;
      }
      if (lane < ROWS) rs[s][lane + 1] = v;
      if (lane == 0)   rs[s][0] = 0;
    }
    __syncthreads();   // sync3

    // ---- phase F: CSR fill with norms ----
    if (t256 < EDG){
      float nrm = deg[s][es] * eww * deg[s][ed];
      int slot = rs[s][ed] + atomicAdd(&cnt2[s][ed], 1);
      c_src[s][slot] = es;
      c_nrm[s][slot] = nrm;
    }
    __syncthreads();   // sync4

    // ---- phase G: gather + bias + residual + LN + ReLU + store ----
    int half = lane >> 5;
    int l32  = lane & 31;
    int c0   = l32 * 4;
    for (int rp = wv4; rp < ROWS / 2; rp += 4){
      int row = 2 * rp + half;
      float dv = deg[s][row];
      float d2 = dv * dv;
      size_t gbase = ((size_t)p * ROWS + row) * CH + c0;
      u16x4 hs = *(const u16x4*)&Hs[s][row][c0];
      f32x4 xr = *(const f32x4*)(x + gbase);
      f32x4 bb = *(const f32x4*)&bia[c0];
      float y0 = bf2f(hs[0]) * d2 + bb[0] + xr[0];
      float y1 = bf2f(hs[1]) * d2 + bb[1] + xr[1];
      float y2 = bf2f(hs[2]) * d2 + bb[2] + xr[2];
      float y3 = bf2f(hs[3]) * d2 + bb[3] + xr[3];
      int s0 = rs[s][row], s1 = rs[s][row + 1];
      for (int i = s0; i < s1; i++){
        int sc = c_src[s][i]; float nm = c_nrm[s][i];
        u16x4 hv = *(const u16x4*)&Hs[s][sc][c0];
        y0 += nm * bf2f(hv[0]);
        y1 += nm * bf2f(hv[1]);
        y2 += nm * bf2f(hv[2]);
        y3 += nm * bf2f(hv[3]);
      }
      float sm = y0 + y1 + y2 + y3;
      float sq = y0*y0 + y1*y1 + y2*y2 + y3*y3;
#pragma unroll
      for (int m = 1; m < 32; m <<= 1){
        sm += __shfl_xor(sm, m, 32);
        sq += __shfl_xor(sq, m, 32);
      }
      float mu   = sm * (1.0f / 128.0f);
      float var  = sq * (1.0f / 128.0f) - mu * mu;
      float rstd = rsqrtf(var + 1e-5f);
      f32x4 g4 = *(const f32x4*)&gam[c0];
      f32x4 b4 = *(const f32x4*)&bet[c0];
      f32x4 o;
      o[0] = fmaxf(0.f, (y0 - mu) * rstd * g4[0] + b4[0]);
      o[1] = fmaxf(0.f, (y1 - mu) * rstd * g4[1] + b4[1]);
      o[2] = fmaxf(0.f, (y2 - mu) * rstd * g4[2] + b4[2]);
      o[3] = fmaxf(0.f, (y3 - mu) * rstd * g4[3] + b4[3]);
      *(f32x4*)(out + gbase) = o;
    }
  }
}

extern "C" void kernel_launch(void* const* d_in, const int* in_sizes, int n_in,
                              void* d_out, int out_size, void* d_ws, size_t ws_size,
                              hipStream_t stream)
{
  const float* x     = (const float*)d_in[0];
  const int*   ei    = (const int*)d_in[1];
  const float* W     = (const float*)d_in[2];
  const float* bias  = (const float*)d_in[3];
  const float* ew    = (const float*)d_in[4];
  const float* gamma = (const float*)d_in[5];
  const float* beta  = (const float*)d_in[6];
  float* out = (float*)d_out;

  int N = in_sizes[0] / CH;          // 458752
  int npairs = N / ROWS;             // 8192
  int ngroups = npairs / 2;          // 4096

  u16* wpack = nullptr;
  if (ws_size >= (size_t)(CH * CH * sizeof(u16))){
    wpack = (u16*)d_ws;
    hipLaunchKernelGGL(pack_w, dim3(CH * CH / 256), dim3(256), 0, stream, W, wpack);
  }

  int grid = ngroups < 1024 ? ngroups : 1024;
  hipLaunchKernelGGL(gcn_fused, dim3(grid), dim3(512), 0, stream,
                     x, ei, W, bias, ew, gamma, beta, out, wpack, npairs);
}